// Round 1
// baseline (567.310 us; speedup 1.0000x reference)
//
#include <hip/hip_runtime.h>
#include <math.h>

// Problem constants
#define NB 32
#define D 64
#define HWD 4096          // 64*64
#define NVEC 131072       // 32*64*64
#define K 1024

// d_out layout (float element offsets, return order: loss, out, perplexity, encodings, inputs)
#define O_LOSS 0
#define O_OUT  1
#define O_PERP 8388609ULL
#define O_ENC  8388610ULL
#define O_INP  142606338ULL   // 8388610 + 134217728

// d_ws layout (bytes)
#define WS_IDX   0          // 131072 int  (524288 B)
#define WS_C2    524288     // 1024 float  (4096 B)
#define WS_HIST  528384     // 1024 int    (4096 B)
#define WS_LPART 532480     // 512 float   (2048 B)

// ---------------------------------------------------------------------------
// Precompute ||c||^2 per code
__global__ void c2_kernel(const float* __restrict__ cb, float* __restrict__ c2) {
    int k = blockIdx.x * blockDim.x + threadIdx.x;
    if (k < K) {
        const float4* row = reinterpret_cast<const float4*>(cb + k * D);
        float s = 0.f;
        #pragma unroll
        for (int q = 0; q < 16; ++q) {
            float4 c = row[q];
            s = fmaf(c.x, c.x, s);
            s = fmaf(c.y, c.y, s);
            s = fmaf(c.z, c.z, s);
            s = fmaf(c.w, c.w, s);
        }
        c2[k] = s;
    }
}

// ---------------------------------------------------------------------------
// Main: per-thread argmin over 1024 codes; also writes transposed inputs,
// idx array, histogram (LDS->global int atomics), per-block loss partials.
__global__ __launch_bounds__(256) void vq_main(
    const float* __restrict__ x, const float* __restrict__ cb,
    const float* __restrict__ c2, float* __restrict__ out,
    int* __restrict__ idx_out, int* __restrict__ hist,
    float* __restrict__ lossPart)
{
    __shared__ int lhist[K];
    __shared__ float lred[4];
    for (int i = threadIdx.x; i < K; i += 256) lhist[i] = 0;

    int n  = blockIdx.x * 256 + threadIdx.x;   // 512 blocks x 256
    int b  = n >> 12;
    int hw = n & 4095;

    // Load x vector (NCHW: stride HWD between channels; coalesced across lanes)
    float xv[D];
    const float* xp = x + (size_t)b * D * HWD + hw;
    #pragma unroll
    for (int d = 0; d < D; ++d) xv[d] = xp[(size_t)d * HWD];

    // Write "inputs" output (NHWC), contiguous per thread
    {
        float4* inp = reinterpret_cast<float4*>(out + O_INP + (size_t)n * D);
        #pragma unroll
        for (int q = 0; q < 16; ++q)
            inp[q] = make_float4(xv[4*q], xv[4*q+1], xv[4*q+2], xv[4*q+3]);
    }

    float sx2 = 0.f;
    #pragma unroll
    for (int d = 0; d < D; ++d) sx2 = fmaf(xv[d], xv[d], sx2);

    // Argmin over codes: score = ||c||^2 - 2 x.c  (order-preserving vs full dist)
    const float4* cb4 = reinterpret_cast<const float4*>(cb);
    float best = 3.4e38f;
    int bestk = 0;
    for (int k = 0; k < K; ++k) {
        float d0 = 0.f, d1 = 0.f, d2 = 0.f, d3 = 0.f;
        #pragma unroll
        for (int q = 0; q < 16; ++q) {
            float4 c = cb4[k * 16 + q];        // wave-uniform address -> s_load
            d0 = fmaf(xv[4*q+0], c.x, d0);
            d1 = fmaf(xv[4*q+1], c.y, d1);
            d2 = fmaf(xv[4*q+2], c.z, d2);
            d3 = fmaf(xv[4*q+3], c.w, d3);
        }
        float score = c2[k] - 2.0f * ((d0 + d1) + (d2 + d3));
        if (score < best) { best = score; bestk = k; }   // strict <: first min, matches argmin
    }

    idx_out[n] = bestk;

    // loss contribution: ||c_best - x||^2 = best + ||x||^2
    float lp = best + sx2;
    #pragma unroll
    for (int off = 32; off > 0; off >>= 1) lp += __shfl_down(lp, off, 64);

    __syncthreads();                    // lhist zero complete
    atomicAdd(&lhist[bestk], 1);
    int wid = threadIdx.x >> 6;
    if ((threadIdx.x & 63) == 0) lred[wid] = lp;
    __syncthreads();

    for (int i = threadIdx.x; i < K; i += 256) {
        int c = lhist[i];
        if (c) atomicAdd(&hist[i], c);  // int atomics: deterministic
    }
    if (threadIdx.x == 0)
        lossPart[blockIdx.x] = (lred[0] + lred[1]) + (lred[2] + lred[3]);
}

// ---------------------------------------------------------------------------
// Quantized output in NCHW: out[b,c,hw] = cb[idx[b*HWD+hw], c]
__global__ __launch_bounds__(256) void outq_kernel(
    const float* __restrict__ cb, const int* __restrict__ idx,
    float* __restrict__ out)
{
    int t  = blockIdx.x * 256 + threadIdx.x;   // 512 blocks
    int b  = t >> 12;
    int hw = t & 4095;
    int k  = idx[t];
    const float4* crow = reinterpret_cast<const float4*>(cb + (size_t)k * D);
    float* ob = out + O_OUT + (size_t)b * D * HWD + hw;
    #pragma unroll
    for (int q = 0; q < 16; ++q) {
        float4 c = crow[q];
        ob[(size_t)(4*q+0) * HWD] = c.x;
        ob[(size_t)(4*q+1) * HWD] = c.y;
        ob[(size_t)(4*q+2) * HWD] = c.z;
        ob[(size_t)(4*q+3) * HWD] = c.w;
    }
}

// ---------------------------------------------------------------------------
// One-hot encodings: one block per row (131072 blocks), 256 threads x float4
__global__ __launch_bounds__(256) void enc_kernel(
    const int* __restrict__ idx, float* __restrict__ out)
{
    int n = blockIdx.x;
    int k = idx[n];                     // broadcast load
    int base = threadIdx.x * 4;
    float4 v;
    v.x = (k == base + 0) ? 1.0f : 0.0f;
    v.y = (k == base + 1) ? 1.0f : 0.0f;
    v.z = (k == base + 2) ? 1.0f : 0.0f;
    v.w = (k == base + 3) ? 1.0f : 0.0f;
    reinterpret_cast<float4*>(out + O_ENC + (size_t)n * K)[threadIdx.x] = v;
}

// ---------------------------------------------------------------------------
// Scalars: perplexity from histogram, loss from partials
__global__ __launch_bounds__(1024) void final_kernel(
    const int* __restrict__ hist, const float* __restrict__ lossPart,
    float* __restrict__ out)
{
    __shared__ float red[1024];
    int t = threadIdx.x;

    float p = (float)hist[t] * (1.0f / (float)NVEC);
    red[t] = p * logf(p + 1e-10f);
    __syncthreads();
    for (int s = 512; s > 0; s >>= 1) {
        if (t < s) red[t] += red[t + s];
        __syncthreads();
    }
    float perp = expf(-red[0]);
    __syncthreads();

    red[t] = (t < 512) ? lossPart[t] : 0.0f;
    __syncthreads();
    for (int s = 512; s > 0; s >>= 1) {
        if (t < s) red[t] += red[t + s];
        __syncthreads();
    }
    if (t == 0) {
        out[O_PERP] = perp;
        out[O_LOSS] = 0.25f * red[0] / 8388608.0f;
    }
}

// ---------------------------------------------------------------------------
extern "C" void kernel_launch(void* const* d_in, const int* in_sizes, int n_in,
                              void* d_out, int out_size, void* d_ws, size_t ws_size,
                              hipStream_t stream) {
    const float* x  = (const float*)d_in[0];
    const float* cb = (const float*)d_in[1];
    float* out = (float*)d_out;

    char* ws = (char*)d_ws;
    int*   idx   = (int*)(ws + WS_IDX);
    float* c2    = (float*)(ws + WS_C2);
    int*   hist  = (int*)(ws + WS_HIST);
    float* lpart = (float*)(ws + WS_LPART);

    // zero histogram (capturable)
    hipMemsetAsync(hist, 0, K * sizeof(int), stream);

    c2_kernel<<<4, 256, 0, stream>>>(cb, c2);
    vq_main<<<NVEC / 256, 256, 0, stream>>>(x, cb, c2, out, idx, hist, lpart);
    final_kernel<<<1, 1024, 0, stream>>>(hist, lpart, out);
    outq_kernel<<<NVEC / 256, 256, 0, stream>>>(cb, idx, out);
    enc_kernel<<<NVEC, 256, 0, stream>>>(idx, out);
}

// Round 2
// 286.334 us; speedup vs baseline: 1.9813x; 1.9813x over previous
//
#include <hip/hip_runtime.h>
#include <math.h>

// Problem constants
#define D 64
#define HWD 4096          // 64*64
#define NVEC 131072       // 32*64*64
#define K 1024

// d_out layout (float element offsets: loss, out, perplexity, encodings, inputs)
#define O_LOSS 0
#define O_OUT  1
#define O_PERP 8388609ULL
#define O_ENC  8388610ULL
#define O_INP  142606338ULL   // 8388610 + 134217728

// d_ws layout (bytes) — total 534528 B (same footprint as round 1)
#define WS_CBH   0          // K*D fp16 B-fragment-packed (131072 B)
#define WS_CBL   131072     // K*D fp16 lo part          (131072 B)
#define WS_C2    262144     // 1024 float                (4096 B)
#define WS_IDX   266240     // 131072 ushort             (262144 B)
#define WS_HIST  528384     // 1024 int                  (4096 B)
#define WS_LPART 532480     // 512 float                 (2048 B)

typedef _Float16 half8 __attribute__((ext_vector_type(8)));
typedef float    f32x16 __attribute__((ext_vector_type(16)));

// ---------------------------------------------------------------------------
// ||c||^2 per code (fp32 exact)
__global__ __launch_bounds__(256) void c2_kernel(const float* __restrict__ cb,
                                                 float* __restrict__ c2) {
    int k = blockIdx.x * blockDim.x + threadIdx.x;
    if (k < K) {
        const float4* row = reinterpret_cast<const float4*>(cb + k * D);
        float s = 0.f;
        #pragma unroll
        for (int q = 0; q < 16; ++q) {
            float4 c = row[q];
            s = fmaf(c.x, c.x, s); s = fmaf(c.y, c.y, s);
            s = fmaf(c.z, c.z, s); s = fmaf(c.w, c.w, s);
        }
        c2[k] = s;
    }
}

// ---------------------------------------------------------------------------
// Pack codebook into MFMA B-fragment layout (fp16 hi/lo).
// Fragment unit u = (kt*4 + s)*64 + lane; lane holds code k = kt*32+(lane&31),
// d = s*16 + (lane>>5)*8 + i, i=0..7  (v_mfma_f32_32x32x16_f16 B layout).
__global__ __launch_bounds__(256) void prep_kernel(const float* __restrict__ cb,
                                                   _Float16* __restrict__ cbh,
                                                   _Float16* __restrict__ cbl) {
    int u  = blockIdx.x * 256 + threadIdx.x;   // 32 blocks -> 8192 units
    int l  = u & 63;
    int s  = (u >> 6) & 3;
    int kt = u >> 8;
    int k  = kt * 32 + (l & 31);
    int d0 = s * 16 + (l >> 5) * 8;
    const float* src = cb + k * D + d0;
    half8 h, lo;
    #pragma unroll
    for (int i = 0; i < 8; ++i) {
        float v = src[i];
        _Float16 hh = (_Float16)v;
        h[i]  = hh;
        lo[i] = (_Float16)(v - (float)hh);
    }
    reinterpret_cast<half8*>(cbh)[u] = h;
    reinterpret_cast<half8*>(cbl)[u] = lo;
}

// ---------------------------------------------------------------------------
// MFMA argmin: block = 64 rows (n) x all 1024 codes; 4 waves partition K.
// score = ||c||^2 - 2*x.c  (order-preserving; fp16 hi/lo, 3 products)
__global__ __launch_bounds__(256, 2) void vq_argmin(
    const float* __restrict__ x, const _Float16* __restrict__ cbh,
    const _Float16* __restrict__ cbl, const float* __restrict__ c2,
    unsigned short* __restrict__ idx_out)
{
    __shared__ float    sb[4][64];
    __shared__ unsigned sk[4][64];

    const int lane = threadIdx.x & 63;
    const int wid  = threadIdx.x >> 6;
    const int col  = lane & 31;
    const int g    = lane >> 5;
    const int n0   = blockIdx.x * 64;
    const int b    = n0 >> 12;
    const int hw0  = n0 & 4095;
    const size_t bbase = (size_t)b << 18;   // b * D * HWD

    // A-fragments: x rows n0+m*32+col, d = s*16 + g*8 + i (fp16 hi/lo)
    half8 ah[2][4], al[2][4];
    #pragma unroll
    for (int m = 0; m < 2; ++m) {
        const float* xp = x + bbase + (hw0 + m * 32 + col);
        #pragma unroll
        for (int s = 0; s < 4; ++s) {
            #pragma unroll
            for (int i = 0; i < 8; ++i) {
                float v = xp[(size_t)(s * 16 + g * 8 + i) << 12];
                _Float16 h = (_Float16)v;
                ah[m][s][i] = h;
                al[m][s][i] = (_Float16)(v - (float)h);
            }
        }
    }

    float    best[2][16];
    unsigned kbest[2][16];
    #pragma unroll
    for (int m = 0; m < 2; ++m)
        #pragma unroll
        for (int r = 0; r < 16; ++r) { best[m][r] = 3.4e38f; kbest[m][r] = 0u; }

    const half8* Bh = reinterpret_cast<const half8*>(cbh);
    const half8* Bl = reinterpret_cast<const half8*>(cbl);

    for (int j = 0; j < 8; ++j) {
        int kt = wid * 8 + j;                  // this wave's 32-code tile
        half8 bh[4], bl_[4];
        #pragma unroll
        for (int s = 0; s < 4; ++s) {
            bh[s]  = Bh[(kt * 4 + s) * 64 + lane];   // coalesced 1KB/instr
            bl_[s] = Bl[(kt * 4 + s) * 64 + lane];
        }
        float    c2v  = c2[kt * 32 + col];
        unsigned kcur = (unsigned)(kt * 32 + col);

        f32x16 a0, a1;
        #pragma unroll
        for (int r = 0; r < 16; ++r) { a0[r] = 0.f; a1[r] = 0.f; }

        #pragma unroll
        for (int s = 0; s < 4; ++s) {
            a0 = __builtin_amdgcn_mfma_f32_32x32x16_f16(ah[0][s], bh[s],  a0, 0, 0, 0);
            a1 = __builtin_amdgcn_mfma_f32_32x32x16_f16(ah[1][s], bh[s],  a1, 0, 0, 0);
            a0 = __builtin_amdgcn_mfma_f32_32x32x16_f16(al[0][s], bh[s],  a0, 0, 0, 0);
            a1 = __builtin_amdgcn_mfma_f32_32x32x16_f16(al[1][s], bh[s],  a1, 0, 0, 0);
            a0 = __builtin_amdgcn_mfma_f32_32x32x16_f16(ah[0][s], bl_[s], a0, 0, 0, 0);
            a1 = __builtin_amdgcn_mfma_f32_32x32x16_f16(ah[1][s], bl_[s], a1, 0, 0, 0);
        }

        #pragma unroll
        for (int r = 0; r < 16; ++r) {
            float s0 = fmaf(-2.0f, a0[r], c2v);
            if (s0 < best[0][r]) { best[0][r] = s0; kbest[0][r] = kcur; }
            float s1 = fmaf(-2.0f, a1[r], c2v);
            if (s1 < best[1][r]) { best[1][r] = s1; kbest[1][r] = kcur; }
        }
    }

    // Per-wave cross-lane argmin over the 32 cols (stay within 32-lane half)
    #pragma unroll
    for (int m = 0; m < 2; ++m) {
        #pragma unroll
        for (int r = 0; r < 16; ++r) {
            float bv = best[m][r]; unsigned kv = kbest[m][r];
            #pragma unroll
            for (int mask = 1; mask <= 16; mask <<= 1) {
                float    ob = __shfl_xor(bv, mask);
                unsigned ok = (unsigned)__shfl_xor((int)kv, mask);
                if (ob < bv || (ob == bv && ok < kv)) { bv = ob; kv = ok; }
            }
            if (col == 0) {
                int row = (r & 3) + 8 * (r >> 2) + 4 * g;   // C layout (m74/m101)
                sb[wid][m * 32 + row] = bv;
                sk[wid][m * 32 + row] = kv;
            }
        }
    }
    __syncthreads();

    // Cross-wave combine (waves hold disjoint ascending k-ranges)
    if (threadIdx.x < 64) {
        int t = threadIdx.x;
        float bv = sb[0][t]; unsigned kv = sk[0][t];
        #pragma unroll
        for (int w = 1; w < 4; ++w) {
            float ob = sb[w][t];
            if (ob < bv) { bv = ob; kv = sk[w][t]; }
        }
        idx_out[n0 + t] = (unsigned short)kv;
    }
}

// ---------------------------------------------------------------------------
// inputs output (NHWC): read x strided (lane-coalesced), write contiguous
__global__ __launch_bounds__(256) void inputs_kernel(const float* __restrict__ x,
                                                     float* __restrict__ out) {
    int n  = blockIdx.x * 256 + threadIdx.x;
    int b  = n >> 12;
    int hw = n & 4095;
    const float* xp = x + ((size_t)b << 18) + hw;
    float4* inp = reinterpret_cast<float4*>(out + O_INP + (size_t)n * D);
    #pragma unroll
    for (int q = 0; q < 16; ++q) {
        float v0 = xp[(size_t)(4 * q + 0) << 12];
        float v1 = xp[(size_t)(4 * q + 1) << 12];
        float v2 = xp[(size_t)(4 * q + 2) << 12];
        float v3 = xp[(size_t)(4 * q + 3) << 12];
        inp[q] = make_float4(v0, v1, v2, v3);
    }
}

// ---------------------------------------------------------------------------
// Quantized NCHW output + exact fp32 loss partials + histogram
__global__ __launch_bounds__(256) void outq_loss(
    const float* __restrict__ cb, const float* __restrict__ x,
    const unsigned short* __restrict__ idx, float* __restrict__ out,
    int* __restrict__ hist, float* __restrict__ lossPart)
{
    __shared__ int lhist[K];
    __shared__ float lred[4];
    for (int i = threadIdx.x; i < K; i += 256) lhist[i] = 0;

    int n  = blockIdx.x * 256 + threadIdx.x;   // 512 blocks
    int b  = n >> 12;
    int hw = n & 4095;
    int k  = idx[n];
    const size_t bbase = (size_t)b << 18;
    const float4* crow = reinterpret_cast<const float4*>(cb + (size_t)k * D);
    float* ob = out + O_OUT + bbase + hw;
    const float* xp = x + bbase + hw;

    float lp = 0.f;
    #pragma unroll
    for (int q = 0; q < 16; ++q) {
        float4 c = crow[q];
        float cv[4] = {c.x, c.y, c.z, c.w};
        #pragma unroll
        for (int jj = 0; jj < 4; ++jj) {
            size_t off = (size_t)(4 * q + jj) << 12;
            float xv = xp[off];
            ob[off] = cv[jj];
            float d = cv[jj] - xv;
            lp = fmaf(d, d, lp);
        }
    }

    #pragma unroll
    for (int off = 32; off > 0; off >>= 1) lp += __shfl_down(lp, off, 64);

    __syncthreads();
    atomicAdd(&lhist[k], 1);
    int wid = threadIdx.x >> 6;
    if ((threadIdx.x & 63) == 0) lred[wid] = lp;
    __syncthreads();

    for (int i = threadIdx.x; i < K; i += 256) {
        int c = lhist[i];
        if (c) atomicAdd(&hist[i], c);   // int atomics: deterministic
    }
    if (threadIdx.x == 0)
        lossPart[blockIdx.x] = (lred[0] + lred[1]) + (lred[2] + lred[3]);
}

// ---------------------------------------------------------------------------
// One-hot encodings: one block per row, 256 threads x float4
__global__ __launch_bounds__(256) void enc_kernel(
    const unsigned short* __restrict__ idx, float* __restrict__ out)
{
    int n = blockIdx.x;
    int k = idx[n];
    int base = threadIdx.x * 4;
    float4 v;
    v.x = (k == base + 0) ? 1.0f : 0.0f;
    v.y = (k == base + 1) ? 1.0f : 0.0f;
    v.z = (k == base + 2) ? 1.0f : 0.0f;
    v.w = (k == base + 3) ? 1.0f : 0.0f;
    reinterpret_cast<float4*>(out + O_ENC + (size_t)n * K)[threadIdx.x] = v;
}

// ---------------------------------------------------------------------------
// Scalars: perplexity from histogram, loss from partials
__global__ __launch_bounds__(1024) void final_kernel(
    const int* __restrict__ hist, const float* __restrict__ lossPart,
    float* __restrict__ out)
{
    __shared__ float red[1024];
    int t = threadIdx.x;

    float p = (float)hist[t] * (1.0f / (float)NVEC);
    red[t] = p * logf(p + 1e-10f);
    __syncthreads();
    for (int s = 512; s > 0; s >>= 1) {
        if (t < s) red[t] += red[t + s];
        __syncthreads();
    }
    float perp = expf(-red[0]);
    __syncthreads();

    red[t] = (t < 512) ? lossPart[t] : 0.0f;
    __syncthreads();
    for (int s = 512; s > 0; s >>= 1) {
        if (t < s) red[t] += red[t + s];
        __syncthreads();
    }
    if (t == 0) {
        out[O_PERP] = perp;
        out[O_LOSS] = 0.25f * red[0] / 8388608.0f;
    }
}

// ---------------------------------------------------------------------------
extern "C" void kernel_launch(void* const* d_in, const int* in_sizes, int n_in,
                              void* d_out, int out_size, void* d_ws, size_t ws_size,
                              hipStream_t stream) {
    const float* x  = (const float*)d_in[0];
    const float* cb = (const float*)d_in[1];
    float* out = (float*)d_out;

    char* ws = (char*)d_ws;
    _Float16* cbh   = (_Float16*)(ws + WS_CBH);
    _Float16* cbl   = (_Float16*)(ws + WS_CBL);
    float*    c2    = (float*)(ws + WS_C2);
    unsigned short* idx = (unsigned short*)(ws + WS_IDX);
    int*      hist  = (int*)(ws + WS_HIST);
    float*    lpart = (float*)(ws + WS_LPART);

    hipMemsetAsync(hist, 0, K * sizeof(int), stream);

    c2_kernel<<<4, 256, 0, stream>>>(cb, c2);
    prep_kernel<<<32, 256, 0, stream>>>(cb, cbh, cbl);
    vq_argmin<<<NVEC / 64, 256, 0, stream>>>(x, cbh, cbl, c2, idx);
    inputs_kernel<<<NVEC / 256, 256, 0, stream>>>(x, out);
    outq_loss<<<NVEC / 256, 256, 0, stream>>>(cb, x, idx, out, hist, lpart);
    final_kernel<<<1, 1024, 0, stream>>>(hist, lpart, out);
    enc_kernel<<<NVEC, 256, 0, stream>>>(idx, out);
}

// Round 4
// 247.492 us; speedup vs baseline: 2.2922x; 1.1569x over previous
//
#include <hip/hip_runtime.h>
#include <math.h>

// Problem constants
#define D 64
#define HWD 4096          // 64*64
#define NVEC 131072       // 32*64*64
#define K 1024

// d_out layout (float element offsets: loss, out, perplexity, encodings, inputs)
#define O_LOSS 0
#define O_OUT  1
#define O_PERP 8388609ULL
#define O_ENC  8388610ULL
#define O_INP  142606338ULL   // 8388610 + 134217728

// d_ws layout (bytes)
#define WS_CBH   0          // K*D fp16 B-fragment-packed (131072 B)
#define WS_CBL   131072     // K*D fp16 lo part           (131072 B)
#define WS_C2    262144     // 1024 float                 (4096 B)
#define WS_HIST  266240     // 1024 int                   (4096 B)
#define WS_LPART 270336     // 2048 float                 (8192 B)

typedef _Float16 half8 __attribute__((ext_vector_type(8)));
typedef float    f32x16 __attribute__((ext_vector_type(16)));
typedef float    f32x4  __attribute__((ext_vector_type(4)));

// ---------------------------------------------------------------------------
// ||c||^2 per code (fp32 exact)
__global__ __launch_bounds__(256) void c2_kernel(const float* __restrict__ cb,
                                                 float* __restrict__ c2) {
    int k = blockIdx.x * blockDim.x + threadIdx.x;
    if (k < K) {
        const float4* row = reinterpret_cast<const float4*>(cb + k * D);
        float s = 0.f;
        #pragma unroll
        for (int q = 0; q < 16; ++q) {
            float4 c = row[q];
            s = fmaf(c.x, c.x, s); s = fmaf(c.y, c.y, s);
            s = fmaf(c.z, c.z, s); s = fmaf(c.w, c.w, s);
        }
        c2[k] = s;
    }
}

// ---------------------------------------------------------------------------
// Pack codebook into MFMA B-fragment layout (fp16 hi/lo).
// unit u = (kt*4 + s)*64 + lane; lane holds code k = kt*32+(lane&31),
// d = s*16 + (lane>>5)*8 + i  (v_mfma_f32_32x32x16_f16 B layout).
__global__ __launch_bounds__(256) void prep_kernel(const float* __restrict__ cb,
                                                   _Float16* __restrict__ cbh,
                                                   _Float16* __restrict__ cbl) {
    int u  = blockIdx.x * 256 + threadIdx.x;   // 32 blocks -> 8192 units
    int l  = u & 63;
    int s  = (u >> 6) & 3;
    int kt = u >> 8;
    int k  = kt * 32 + (l & 31);
    int d0 = s * 16 + (l >> 5) * 8;
    const float* src = cb + k * D + d0;
    half8 h, lo;
    #pragma unroll
    for (int i = 0; i < 8; ++i) {
        float v = src[i];
        _Float16 hh = (_Float16)v;
        h[i]  = hh;
        lo[i] = (_Float16)(v - (float)hh);
    }
    reinterpret_cast<half8*>(cbh)[u] = h;
    reinterpret_cast<half8*>(cbl)[u] = lo;
}

// ---------------------------------------------------------------------------
// Fused: per block = 64 rows. MFMA argmin over all 1024 codes (4 waves
// partition K), then writes inputs(NHWC), quantized(NCHW), one-hot encodings,
// loss partial, histogram — all from this block, overlapping other blocks'
// MFMA with this block's streaming stores.
__global__ __launch_bounds__(256, 2) void vq_fused(
    const float* __restrict__ x, const float* __restrict__ cb,
    const _Float16* __restrict__ cbh, const _Float16* __restrict__ cbl,
    const float* __restrict__ c2, float* __restrict__ out,
    int* __restrict__ hist, float* __restrict__ lossPart)
{
    __shared__ float    sb[4][64];
    __shared__ unsigned sk[4][64];
    __shared__ float    ssx[64];
    __shared__ unsigned skf[64];

    const int lane = threadIdx.x & 63;
    const int wid  = threadIdx.x >> 6;
    const int col  = lane & 31;
    const int g    = lane >> 5;
    const int n0   = blockIdx.x * 64;
    const int b    = n0 >> 12;
    const int hw0  = n0 & 4095;
    const size_t bbase = (size_t)b << 18;   // b * D * HWD

    // ---- Phase 0: load x rows (fp32), write "inputs" (wave 0 only), sx2,
    //      convert to fp16 hi/lo A-fragments.
    float xv[2][4][8];
    #pragma unroll
    for (int m = 0; m < 2; ++m) {
        const float* xp = x + bbase + (hw0 + m * 32 + col);
        #pragma unroll
        for (int s = 0; s < 4; ++s)
            #pragma unroll
            for (int i = 0; i < 8; ++i)
                xv[m][s][i] = xp[(size_t)(s * 16 + g * 8 + i) << 12];
    }

    if (wid == 0) {
        #pragma unroll
        for (int m = 0; m < 2; ++m) {
            float* ip = out + O_INP + (size_t)(n0 + m * 32 + col) * 64 + g * 8;
            #pragma unroll
            for (int s = 0; s < 4; ++s) {
                f32x4 v0 = {xv[m][s][0], xv[m][s][1], xv[m][s][2], xv[m][s][3]};
                f32x4 v1 = {xv[m][s][4], xv[m][s][5], xv[m][s][6], xv[m][s][7]};
                __builtin_nontemporal_store(v0, reinterpret_cast<f32x4*>(ip + s * 16));
                __builtin_nontemporal_store(v1, reinterpret_cast<f32x4*>(ip + s * 16 + 4));
            }
        }
    }

    #pragma unroll
    for (int m = 0; m < 2; ++m) {
        float sp = 0.f;
        #pragma unroll
        for (int s = 0; s < 4; ++s)
            #pragma unroll
            for (int i = 0; i < 8; ++i)
                sp = fmaf(xv[m][s][i], xv[m][s][i], sp);
        sp += __shfl_xor(sp, 32, 64);          // combine g halves
        if (wid == 0 && g == 0) ssx[m * 32 + col] = sp;
    }

    half8 ah[2][4], al[2][4];
    #pragma unroll
    for (int m = 0; m < 2; ++m)
        #pragma unroll
        for (int s = 0; s < 4; ++s)
            #pragma unroll
            for (int i = 0; i < 8; ++i) {
                _Float16 h = (_Float16)xv[m][s][i];
                ah[m][s][i] = h;
                al[m][s][i] = (_Float16)(xv[m][s][i] - (float)h);
            }

    // ---- Phase 1: MFMA argmin. score = ||c||^2 - 2 x.c
    float    best[2][16];
    unsigned kbest[2][16];
    #pragma unroll
    for (int m = 0; m < 2; ++m)
        #pragma unroll
        for (int r = 0; r < 16; ++r) { best[m][r] = 3.4e38f; kbest[m][r] = 0u; }

    const half8* Bh = reinterpret_cast<const half8*>(cbh);
    const half8* Bl = reinterpret_cast<const half8*>(cbl);

    for (int j = 0; j < 8; ++j) {
        int kt = wid * 8 + j;                  // this wave's 32-code tile
        half8 bh[4], bl_[4];
        #pragma unroll
        for (int s = 0; s < 4; ++s) {
            bh[s]  = Bh[(kt * 4 + s) * 64 + lane];   // coalesced 1KB/instr
            bl_[s] = Bl[(kt * 4 + s) * 64 + lane];
        }
        float    c2v  = c2[kt * 32 + col];
        unsigned kcur = (unsigned)(kt * 32 + col);

        f32x16 a0, a1;
        #pragma unroll
        for (int r = 0; r < 16; ++r) { a0[r] = 0.f; a1[r] = 0.f; }

        #pragma unroll
        for (int s = 0; s < 4; ++s) {
            a0 = __builtin_amdgcn_mfma_f32_32x32x16_f16(ah[0][s], bh[s],  a0, 0, 0, 0);
            a1 = __builtin_amdgcn_mfma_f32_32x32x16_f16(ah[1][s], bh[s],  a1, 0, 0, 0);
            a0 = __builtin_amdgcn_mfma_f32_32x32x16_f16(al[0][s], bh[s],  a0, 0, 0, 0);
            a1 = __builtin_amdgcn_mfma_f32_32x32x16_f16(al[1][s], bh[s],  a1, 0, 0, 0);
            a0 = __builtin_amdgcn_mfma_f32_32x32x16_f16(ah[0][s], bl_[s], a0, 0, 0, 0);
            a1 = __builtin_amdgcn_mfma_f32_32x32x16_f16(ah[1][s], bl_[s], a1, 0, 0, 0);
        }

        #pragma unroll
        for (int r = 0; r < 16; ++r) {
            float s0 = fmaf(-2.0f, a0[r], c2v);
            if (s0 < best[0][r]) { best[0][r] = s0; kbest[0][r] = kcur; }
            float s1 = fmaf(-2.0f, a1[r], c2v);
            if (s1 < best[1][r]) { best[1][r] = s1; kbest[1][r] = kcur; }
        }
    }

    // Per-wave cross-lane argmin over the 32 cols
    #pragma unroll
    for (int m = 0; m < 2; ++m) {
        #pragma unroll
        for (int r = 0; r < 16; ++r) {
            float bv = best[m][r]; unsigned kv = kbest[m][r];
            #pragma unroll
            for (int mask = 1; mask <= 16; mask <<= 1) {
                float    ob = __shfl_xor(bv, mask);
                unsigned ok = (unsigned)__shfl_xor((int)kv, mask);
                if (ob < bv || (ob == bv && ok < kv)) { bv = ob; kv = ok; }
            }
            if (col == 0) {
                int row = (r & 3) + 8 * (r >> 2) + 4 * g;   // C layout (m74/m101)
                sb[wid][m * 32 + row] = bv;
                sk[wid][m * 32 + row] = kv;
            }
        }
    }
    __syncthreads();

    // ---- Phase 2: cross-wave combine, loss partial, histogram
    if (threadIdx.x < 64) {
        int t = threadIdx.x;
        float bv = sb[0][t]; unsigned kv = sk[0][t];
        #pragma unroll
        for (int w = 1; w < 4; ++w) {
            float ob = sb[w][t];
            if (ob < bv) { bv = ob; kv = sk[w][t]; }
        }
        skf[t] = kv;
        atomicAdd(&hist[kv], 1);
        float lp = bv + ssx[t];                 // ||c-x||^2 = score + ||x||^2
        #pragma unroll
        for (int off = 32; off > 0; off >>= 1) lp += __shfl_down(lp, off, 64);
        if (t == 0) lossPart[blockIdx.x] = lp;
    }
    __syncthreads();

    // ---- Phase 3: quantized NCHW. wave w -> 16 channels, lane -> row.
    {
        unsigned kr = skf[lane];
        const float* crow = cb + (size_t)kr * D;
        float* ob = out + O_OUT + bbase + hw0 + lane;
        #pragma unroll
        for (int c16 = 0; c16 < 16; ++c16) {
            int c = wid * 16 + c16;
            __builtin_nontemporal_store(crow[c], ob + ((size_t)c << 12));
        }
    }

    // ---- Phase 4: one-hot encodings, 64 rows x 4KB, coalesced float4 stores
    {
        int base = threadIdx.x * 4;
        float* eb = out + O_ENC + (size_t)n0 * K + base;
        for (int r = 0; r < 64; ++r) {
            int k = (int)skf[r];
            f32x4 v;
            v[0] = (k == base + 0) ? 1.0f : 0.0f;
            v[1] = (k == base + 1) ? 1.0f : 0.0f;
            v[2] = (k == base + 2) ? 1.0f : 0.0f;
            v[3] = (k == base + 3) ? 1.0f : 0.0f;
            __builtin_nontemporal_store(v, reinterpret_cast<f32x4*>(eb + (size_t)r * K));
        }
    }
}

// ---------------------------------------------------------------------------
// Scalars: perplexity from histogram, loss from 2048 partials
__global__ __launch_bounds__(1024) void final_kernel(
    const int* __restrict__ hist, const float* __restrict__ lossPart,
    float* __restrict__ out)
{
    __shared__ float red[1024];
    int t = threadIdx.x;

    float p = (float)hist[t] * (1.0f / (float)NVEC);
    red[t] = p * logf(p + 1e-10f);
    __syncthreads();
    for (int s = 512; s > 0; s >>= 1) {
        if (t < s) red[t] += red[t + s];
        __syncthreads();
    }
    float perp = expf(-red[0]);
    __syncthreads();

    red[t] = lossPart[t] + lossPart[t + 1024];
    __syncthreads();
    for (int s = 512; s > 0; s >>= 1) {
        if (t < s) red[t] += red[t + s];
        __syncthreads();
    }
    if (t == 0) {
        out[O_PERP] = perp;
        out[O_LOSS] = 0.25f * red[0] / 8388608.0f;
    }
}

// ---------------------------------------------------------------------------
extern "C" void kernel_launch(void* const* d_in, const int* in_sizes, int n_in,
                              void* d_out, int out_size, void* d_ws, size_t ws_size,
                              hipStream_t stream) {
    const float* x  = (const float*)d_in[0];
    const float* cb = (const float*)d_in[1];
    float* out = (float*)d_out;

    char* ws = (char*)d_ws;
    _Float16* cbh   = (_Float16*)(ws + WS_CBH);
    _Float16* cbl   = (_Float16*)(ws + WS_CBL);
    float*    c2    = (float*)(ws + WS_C2);
    int*      hist  = (int*)(ws + WS_HIST);
    float*    lpart = (float*)(ws + WS_LPART);

    (void)hipMemsetAsync(hist, 0, K * sizeof(int), stream);

    c2_kernel<<<4, 256, 0, stream>>>(cb, c2);
    prep_kernel<<<32, 256, 0, stream>>>(cb, cbh, cbl);
    vq_fused<<<NVEC / 64, 256, 0, stream>>>(x, cb, cbh, cbl, c2, out, hist, lpart);
    final_kernel<<<1, 1024, 0, stream>>>(hist, lpart, out);
}